// Round 11
// baseline (262.759 us; speedup 1.0000x reference)
//
#include <hip/hip_runtime.h>
#include <stdint.h>

#define TEMP_ 0.75f
#define EPS_ 1e-6f

typedef __attribute__((ext_vector_type(8))) short bf16x8;
typedef __attribute__((ext_vector_type(4))) float f32x4;

typedef __attribute__((address_space(1))) void gvoid_t;
typedef __attribute__((address_space(3))) void lvoid_t;

__device__ __forceinline__ void async_ld16(const void* g, void* l) {
  __builtin_amdgcn_global_load_lds((gvoid_t*)g, (lvoid_t*)l, 16, 0, 0);
}

__device__ __forceinline__ float b2f(ushort u) {
  return __builtin_bit_cast(float, (uint32_t)u << 16);
}
__device__ __forceinline__ ushort f2b(float f) {
  uint32_t x = __builtin_bit_cast(uint32_t, f);
  x += 0x7fffu + ((x >> 16) & 1u);
  return (ushort)(x >> 16);
}

// LDS byte-offset of a __shared__ address (AS3 pointers are 32-bit offsets)
__device__ __forceinline__ uint32_t lds_u32(const void* p) {
  return (uint32_t)(uintptr_t)(lvoid_t*)p;
}

// volatile asm ds_read_b128: all lgkm/vm waiting is explicit (rule 18 discipline).
__device__ __forceinline__ bf16x8 dsr(uint32_t addr) {
  bf16x8 d;
  asm volatile("ds_read_b128 %0, %1" : "=v"(d) : "v"(addr));
  return d;
}

// ------------------------------------------------------- prep_x: fp32 x -> bf16 xb + fp32 half-bucket sums
// 512 blocks (column-split): 2 blocks/CU for TLP; per-column serial sum order unchanged (bitwise).
__global__ __launch_bounds__(256) void prep_x(
    const float* __restrict__ x, ushort* __restrict__ xb, float* __restrict__ xsum2) {
  const int hb = blockIdx.x >> 1;   // half-bucket index (old blk), 0..255
  const int ch = blockIdx.x & 1;    // column half
  const int bu = hb >> 1, half = hb & 1;
  const int b = bu >> 6, u = bu & 63;
  const int c = ch * 512 + threadIdx.x * 2;
  const float* src = x + ((size_t)(b * 4096 + u * 64 + half * 32)) * 1024 + c;
  ushort* dst = xb + ((size_t)(b * 4096 + u * 64 + half * 32)) * 1024 + c;
  float s0 = 0.f, s1 = 0.f;
  #pragma unroll 4
  for (int pos = 0; pos < 32; pos++) {
    float2 v = *(const float2*)(src + (size_t)pos * 1024);
    s0 += v.x; s1 += v.y;
    ushort2 o;
    o.x = f2b(v.x); o.y = f2b(v.y);
    *(ushort2*)(dst + (size_t)pos * 1024) = o;
  }
  float2 sv = {s0, s1};
  *(float2*)&xsum2[(size_t)hb * 1024 + c] = sv;
}

// ------------------------------------------------------- transpose + fp32->bf16
__global__ __launch_bounds__(256) void transpose_f2b(
    const float* __restrict__ src, ushort* __restrict__ dst, int R, int C) {
  __shared__ float tile[32][33];
  int bx = blockIdx.x * 32;
  int by = blockIdx.y * 32;
  int tx = threadIdx.x & 31, ty = threadIdx.x >> 5;  // 32 x 8
  #pragma unroll
  for (int i = 0; i < 32; i += 8)
    tile[ty + i][tx] = src[(size_t)(by + ty + i) * C + bx + tx];
  __syncthreads();
  #pragma unroll
  for (int i = 0; i < 32; i += 8)
    dst[(size_t)(bx + ty + i) * R + by + tx] = f2b(tile[tx][ty + i]);
}

// ------------------------------------------------------- sx partial: split-K over 8 chunks
// SXP[kc*128 + bu][n]  (n in [0,2048)); unroll 4 for load ILP (per-acc fp order unchanged)
__global__ __launch_bounds__(256) void sx_gemm_partial(
    const float* __restrict__ xsum2, const float* __restrict__ wqkv,
    float* __restrict__ SXP) {
  __shared__ float xs[128 * 8];  // k-major: xs[k*8 + r]
  const int cb = blockIdx.x;  // 8 colblocks of 256 n
  const int rt = blockIdx.y;  // 16 rowtiles of 8 bu
  const int kc = blockIdx.z;  // 8 k-chunks of 128
  const int tid = threadIdx.x;
  for (int idx = tid; idx < 1024; idx += 256) {
    int k = idx >> 3, r = idx & 7;
    int bu = rt * 8 + r;
    int kk = kc * 128 + k;
    xs[idx] = xsum2[(size_t)(bu * 2) * 1024 + kk] + xsum2[(size_t)(bu * 2 + 1) * 1024 + kk];
  }
  __syncthreads();
  const int n = cb * 256 + tid;
  float acc[8];
  #pragma unroll
  for (int r = 0; r < 8; r++) acc[r] = 0.f;
  #pragma unroll 4
  for (int k = 0; k < 128; k++) {
    float w = wqkv[(size_t)(kc * 128 + k) * 3072 + n];
    float4 a0 = *(const float4*)&xs[k * 8];
    float4 a1 = *(const float4*)&xs[k * 8 + 4];
    acc[0] += a0.x * w; acc[1] += a0.y * w; acc[2] += a0.z * w; acc[3] += a0.w * w;
    acc[4] += a1.x * w; acc[5] += a1.y * w; acc[6] += a1.z * w; acc[7] += a1.w * w;
  }
  #pragma unroll
  for (int r = 0; r < 8; r++)
    SXP[(size_t)(kc * 128 + rt * 8 + r) * 2048 + n] = acc[r];
}

// ------------------------------------------------------- sx reduce: fixed-order sum + scatter
// SX layout: [bh][e2(256)][u(64)]
__global__ __launch_bounds__(256) void sx_reduce(
    const float* __restrict__ SXP, float* __restrict__ SX) {
  const int bu = blockIdx.y;
  const int n = blockIdx.x * 256 + threadIdx.x;
  float s = 0.f;
  #pragma unroll
  for (int kc = 0; kc < 8; kc++)
    s += SXP[(size_t)(kc * 128 + bu) * 2048 + n];
  const int head = (n >> 7) & 7;
  const int e2 = ((n >> 10) << 7) | (n & 127);
  const int b = bu >> 6, u = bu & 63;
  SX[((size_t)((b * 8 + head) * 256) + e2) * 64 + u] = s;
}

// ------------------------------------------------------- sortnet + sinkhorn + top1 (fp32, LDS-staged)
// Sinkhorn reductions via 4-adjacent-lane shuffles (bitwise-identical combine order).
__global__ __launch_bounds__(256) void sortnet_sinkhorn(
    const float* __restrict__ SX, const float* __restrict__ sortw,
    const float* __restrict__ gum, int* __restrict__ idxArr,
    float* __restrict__ wgtArr) {
  __shared__ float sxl[64 * 64];  // chunk: [e][u]  16 KB
  __shared__ float wl[64 * 64];   // chunk: [e][c]  16 KB
  __shared__ float rr[64 * 65];   // 16.6 KB
  const int bh = blockIdx.x, tid = threadIdx.x, head = bh & 7;
  const int ui = tid & 15, ci = tid >> 4;  // 4x4 tile position

  float acc[4][4];
  #pragma unroll
  for (int i = 0; i < 4; i++)
    #pragma unroll
    for (int j = 0; j < 4; j++) acc[i][j] = 0.f;

  const f32x4* SX4 = (const f32x4*)(SX + (size_t)bh * 16384);
  const f32x4* W4 = (const f32x4*)(sortw + (size_t)head * 16384);
  f32x4* sxl4 = (f32x4*)sxl;
  f32x4* wl4 = (f32x4*)wl;

  #pragma unroll 1
  for (int ch = 0; ch < 4; ch++) {
    __syncthreads();
    #pragma unroll 1
    for (int g = tid; g < 1024; g += 256) {
      sxl4[g] = SX4[ch * 1024 + g];
      wl4[g] = W4[ch * 1024 + g];
    }
    __syncthreads();
    #pragma unroll 2
    for (int e = 0; e < 64; e++) {
      f32x4 a = sxl4[e * 16 + ui];
      f32x4 w = wl4[e * 16 + ci];
      #pragma unroll
      for (int i = 0; i < 4; i++)
        #pragma unroll
        for (int j = 0; j < 4; j++) acc[i][j] += a[i] * w[j];
    }
  }

  // leaky relu + gumbel + log -> rr
  #pragma unroll
  for (int i = 0; i < 4; i++)
    #pragma unroll
    for (int j = 0; j < 4; j++) {
      int u = ui * 4 + i, c = ci * 4 + j;
      float dot = acc[i][j];
      float r0 = dot > 0.f ? dot : 0.01f * dot;
      float gu = gum[(size_t)bh * 4096 + u * 64 + c];
      float inner = -logf(gu + EPS_) + EPS_;
      float g = -logf(fmaxf(inner, 1e-38f));
      rr[u * 65 + c] = (logf(fmaxf(r0 + EPS_, EPS_)) + g) / TEMP_;
    }
  __syncthreads();

  // 4 adjacent lanes own one row (row norm) / one col (col norm); qq = quarter.
  const int row4 = tid >> 2, qq = tid & 3;
  #pragma unroll 1
  for (int it = 0; it < 5; it++) {
    {  // row norm (axis c)
      float pm = -1e30f;
      #pragma unroll
      for (int j = 0; j < 16; j++) pm = fmaxf(pm, rr[row4 * 65 + qq * 16 + j]);
      float m0 = __shfl(pm, 0, 4), m1 = __shfl(pm, 1, 4);
      float m2 = __shfl(pm, 2, 4), m3 = __shfl(pm, 3, 4);
      float m = fmaxf(fmaxf(m0, m1), fmaxf(m2, m3));
      float ps = 0.f;
      #pragma unroll
      for (int j = 0; j < 16; j++) ps += expf(rr[row4 * 65 + qq * 16 + j] - m);
      float s0 = __shfl(ps, 0, 4), s1 = __shfl(ps, 1, 4);
      float s2 = __shfl(ps, 2, 4), s3 = __shfl(ps, 3, 4);
      float l = m + logf(((s0 + s1) + s2) + s3);
      #pragma unroll
      for (int j = 0; j < 16; j++) rr[row4 * 65 + qq * 16 + j] -= l;
      __syncthreads();
    }
    {  // col norm (axis u)
      float pm = -1e30f;
      #pragma unroll
      for (int j = 0; j < 16; j++) pm = fmaxf(pm, rr[(qq * 16 + j) * 65 + row4]);
      float m0 = __shfl(pm, 0, 4), m1 = __shfl(pm, 1, 4);
      float m2 = __shfl(pm, 2, 4), m3 = __shfl(pm, 3, 4);
      float m = fmaxf(fmaxf(m0, m1), fmaxf(m2, m3));
      float ps = 0.f;
      #pragma unroll
      for (int j = 0; j < 16; j++) ps += expf(rr[(qq * 16 + j) * 65 + row4] - m);
      float s0 = __shfl(ps, 0, 4), s1 = __shfl(ps, 1, 4);
      float s2 = __shfl(ps, 2, 4), s3 = __shfl(ps, 3, 4);
      float l = m + logf(((s0 + s1) + s2) + s3);
      #pragma unroll
      for (int j = 0; j < 16; j++) rr[(qq * 16 + j) * 65 + row4] -= l;
      __syncthreads();
    }
  }

  {  // first-max argmax over cols (np semantics): per-quarter scan then q-ascending strict >
    float pv = -1e30f;
    int pi = 0;
    #pragma unroll
    for (int j = 0; j < 16; j++) {
      float v = rr[row4 * 65 + qq * 16 + j];
      if (v > pv) { pv = v; pi = qq * 16 + j; }
    }
    float v0 = __shfl(pv, 0, 4); int i0 = __shfl(pi, 0, 4);
    float v1 = __shfl(pv, 1, 4); int i1 = __shfl(pi, 1, 4);
    float v2 = __shfl(pv, 2, 4); int i2 = __shfl(pi, 2, 4);
    float v3 = __shfl(pv, 3, 4); int i3 = __shfl(pi, 3, 4);
    float best = -1e30f;
    int bi = 0;
    if (v0 > best) { best = v0; bi = i0; }
    if (v1 > best) { best = v1; bi = i1; }
    if (v2 > best) { best = v2; bi = i2; }
    if (v3 > best) { best = v3; bi = i3; }
    if (qq == 0) {
      idxArr[bh * 64 + row4] = bi;
      wgtArr[bh * 64 + row4] = expf(fminf(best, 80.f));
    }
  }
}

// ------------------------------------------------------- QKV GEMM (r8 best-measured: 58.6us):
// 128^2 tile, BK=64, 2 blocks/CU, T2 swizzle (0 conflicts), counted vmcnt(8), split lgkm,
// T1 bijective XCD swizzle, setprio, K=1024 constant-folded.
__global__ __launch_bounds__(256, 2) void gemm_qkv(
    const ushort* __restrict__ A, const ushort* __restrict__ BT,
    ushort* __restrict__ Qb, ushort* __restrict__ Kb, ushort* __restrict__ VT) {
  const int K = 1024;
  __shared__ ushort As[2][128 * 64];
  __shared__ ushort Bs[2][128 * 64];
  const int tid = threadIdx.x;
  const int wave = tid >> 6, lane = tid & 63;
  const int quad = lane >> 4, l16 = lane & 15;
  const int gx = gridDim.x;
  const int lin = blockIdx.y * gx + blockIdx.x;
  const int nwg = gx * gridDim.y;
  const int swz = (lin & 7) * (nwg >> 3) + (lin >> 3);
  const int bx = swz % gx, by = swz / gx;
  const int m0 = by * 128, n0 = bx * 128;
  const int wm = (wave >> 1) * 64, wn = (wave & 1) * 64;
  const ushort* Ap = A + (uint64_t)m0 * K;
  const ushort* Bp = BT + (uint64_t)n0 * K;

  auto stage = [&](const ushort* G, int k0, ushort* buf) {
    #pragma unroll
    for (int q = 0; q < 4; ++q) {
      int p = q * 256 + tid;
      int row = p >> 3, pp = p & 7;
      int cc = pp ^ (row & 7);
      async_ld16(G + (uint64_t)row * K + k0 + cc * 8,
                 buf + (q * 256 + wave * 64) * 8);
    }
  };

  const uint32_t asB = lds_u32(&As[0][0]);
  const uint32_t bsB = lds_u32(&Bs[0][0]);
  uint32_t aoff[2][4], boff[2][4];
  #pragma unroll
  for (int kk = 0; kk < 2; ++kk) {
    int pc = (kk * 4 + quad) ^ (l16 & 7);
    #pragma unroll
    for (int mt = 0; mt < 4; ++mt) {
      aoff[kk][mt] = (uint32_t)((wm + mt * 16 + l16) * 128 + pc * 16);
      boff[kk][mt] = (uint32_t)((wn + mt * 16 + l16) * 128 + pc * 16);
    }
  }

  f32x4 acc[4][4];
  #pragma unroll
  for (int i = 0; i < 4; i++)
    #pragma unroll
    for (int j = 0; j < 4; j++) acc[i][j] = (f32x4){0.f, 0.f, 0.f, 0.f};

  const int NT = K >> 6;  // 16
  stage(Ap, 0, As[0]);
  stage(Bp, 0, Bs[0]);
  stage(Ap, 64, As[1]);
  stage(Bp, 64, Bs[1]);

  #pragma unroll 1
  for (int t = 0; t < NT; ++t) {
    if (t < NT - 1)
      asm volatile("s_waitcnt vmcnt(8)\n\ts_barrier" ::: "memory");
    else
      asm volatile("s_waitcnt vmcnt(0)\n\ts_barrier" ::: "memory");

    const uint32_t ab = asB + (uint32_t)(t & 1) * 16384u;
    const uint32_t bb = bsB + (uint32_t)(t & 1) * 16384u;
    bf16x8 a[2][4], b[2][4];
    #pragma unroll
    for (int kk = 0; kk < 2; ++kk) {
      #pragma unroll
      for (int mt = 0; mt < 4; ++mt) a[kk][mt] = dsr(ab + aoff[kk][mt]);
      #pragma unroll
      for (int nt = 0; nt < 4; ++nt) b[kk][nt] = dsr(bb + boff[kk][nt]);
    }
    asm volatile("s_waitcnt lgkmcnt(8)" ::: "memory");
    __builtin_amdgcn_sched_barrier(0);
    __builtin_amdgcn_s_setprio(1);
    #pragma unroll
    for (int mt = 0; mt < 4; ++mt)
      #pragma unroll
      for (int nt = 0; nt < 4; ++nt)
        acc[mt][nt] = __builtin_amdgcn_mfma_f32_16x16x32_bf16(a[0][mt], b[0][nt], acc[mt][nt], 0, 0, 0);
    __builtin_amdgcn_s_setprio(0);
    asm volatile("s_waitcnt lgkmcnt(0)" ::: "memory");
    __builtin_amdgcn_sched_barrier(0);
    __builtin_amdgcn_s_setprio(1);
    #pragma unroll
    for (int mt = 0; mt < 4; ++mt)
      #pragma unroll
      for (int nt = 0; nt < 4; ++nt)
        acc[mt][nt] = __builtin_amdgcn_mfma_f32_16x16x32_bf16(a[1][mt], b[1][nt], acc[mt][nt], 0, 0, 0);
    __builtin_amdgcn_s_setprio(0);
    asm volatile("s_barrier" ::: "memory");
    if (t + 2 < NT) {
      stage(Ap, (t + 2) * 64, As[t & 1]);
      stage(Bp, (t + 2) * 64, Bs[t & 1]);
    }
  }

  int which = bx >> 3;  // 0=q,1=k,2=v  (n0 multiple of 128)
  int head = bx & 7;
  #pragma unroll
  for (int mt = 0; mt < 4; mt++) {
    int mrow = m0 + wm + mt * 16 + quad * 4;
    int bidx = mrow >> 12;
    int ttok = mrow & 4095;
    int u = ttok >> 6, pos = ttok & 63;
    int bh = bidx * 8 + head;
    #pragma unroll
    for (int nt = 0; nt < 4; nt++) {
      int e = wn + nt * 16 + l16;
      if (which == 2) {
        ushort4 pk;
        pk.x = f2b(acc[mt][nt][0]);
        pk.y = f2b(acc[mt][nt][1]);
        pk.z = f2b(acc[mt][nt][2]);
        pk.w = f2b(acc[mt][nt][3]);
        *(ushort4*)&VT[((uint64_t)(bh * 64 + u) * 128 + e) * 64 + pos] = pk;
      } else {
        ushort* dst = (which == 0) ? Qb : Kb;
        #pragma unroll
        for (int r = 0; r < 4; r++)
          dst[((uint64_t)(bh * 64 + u) * 64 + pos + r) * 128 + e] = f2b(acc[mt][nt][r]);
      }
    }
  }
}

// ------------------------------------------------------- out-proj GEMM: exact clone of the
// validated gemm_qkv loop (counted vmcnt + split lgkm + T2 swizzle + XCD swizzle + setprio,
// K=1024 folded), with the mode-0 bias epilogue. M=8192, N=1024 -> grid (8,64), nwg%8==0.
__global__ __launch_bounds__(256, 2) void gemm_out(
    const ushort* __restrict__ A, const ushort* __restrict__ BT,
    const float* __restrict__ bias, float* __restrict__ Cout) {
  const int K = 1024, N = 1024;
  __shared__ ushort As[2][128 * 64];
  __shared__ ushort Bs[2][128 * 64];
  const int tid = threadIdx.x;
  const int wave = tid >> 6, lane = tid & 63;
  const int quad = lane >> 4, l16 = lane & 15;
  const int gx = gridDim.x;
  const int lin = blockIdx.y * gx + blockIdx.x;
  const int nwg = gx * gridDim.y;
  const int swz = (lin & 7) * (nwg >> 3) + (lin >> 3);
  const int bx = swz % gx, by = swz / gx;
  const int m0 = by * 128, n0 = bx * 128;
  const int wm = (wave >> 1) * 64, wn = (wave & 1) * 64;
  const ushort* Ap = A + (uint64_t)m0 * K;
  const ushort* Bp = BT + (uint64_t)n0 * K;

  auto stage = [&](const ushort* G, int k0, ushort* buf) {
    #pragma unroll
    for (int q = 0; q < 4; ++q) {
      int p = q * 256 + tid;
      int row = p >> 3, pp = p & 7;
      int cc = pp ^ (row & 7);
      async_ld16(G + (uint64_t)row * K + k0 + cc * 8,
                 buf + (q * 256 + wave * 64) * 8);
    }
  };

  const uint32_t asB = lds_u32(&As[0][0]);
  const uint32_t bsB = lds_u32(&Bs[0][0]);
  uint32_t aoff[2][4], boff[2][4];
  #pragma unroll
  for (int kk = 0; kk < 2; ++kk) {
    int pc = (kk * 4 + quad) ^ (l16 & 7);
    #pragma unroll
    for (int mt = 0; mt < 4; ++mt) {
      aoff[kk][mt] = (uint32_t)((wm + mt * 16 + l16) * 128 + pc * 16);
      boff[kk][mt] = (uint32_t)((wn + mt * 16 + l16) * 128 + pc * 16);
    }
  }

  f32x4 acc[4][4];
  #pragma unroll
  for (int i = 0; i < 4; i++)
    #pragma unroll
    for (int j = 0; j < 4; j++) acc[i][j] = (f32x4){0.f, 0.f, 0.f, 0.f};

  const int NT = K >> 6;  // 16
  stage(Ap, 0, As[0]);
  stage(Bp, 0, Bs[0]);
  stage(Ap, 64, As[1]);
  stage(Bp, 64, Bs[1]);

  #pragma unroll 1
  for (int t = 0; t < NT; ++t) {
    if (t < NT - 1)
      asm volatile("s_waitcnt vmcnt(8)\n\ts_barrier" ::: "memory");
    else
      asm volatile("s_waitcnt vmcnt(0)\n\ts_barrier" ::: "memory");

    const uint32_t ab = asB + (uint32_t)(t & 1) * 16384u;
    const uint32_t bb = bsB + (uint32_t)(t & 1) * 16384u;
    bf16x8 a[2][4], b[2][4];
    #pragma unroll
    for (int kk = 0; kk < 2; ++kk) {
      #pragma unroll
      for (int mt = 0; mt < 4; ++mt) a[kk][mt] = dsr(ab + aoff[kk][mt]);
      #pragma unroll
      for (int nt = 0; nt < 4; ++nt) b[kk][nt] = dsr(bb + boff[kk][nt]);
    }
    asm volatile("s_waitcnt lgkmcnt(8)" ::: "memory");
    __builtin_amdgcn_sched_barrier(0);
    __builtin_amdgcn_s_setprio(1);
    #pragma unroll
    for (int mt = 0; mt < 4; ++mt)
      #pragma unroll
      for (int nt = 0; nt < 4; ++nt)
        acc[mt][nt] = __builtin_amdgcn_mfma_f32_16x16x32_bf16(a[0][mt], b[0][nt], acc[mt][nt], 0, 0, 0);
    __builtin_amdgcn_s_setprio(0);
    asm volatile("s_waitcnt lgkmcnt(0)" ::: "memory");
    __builtin_amdgcn_sched_barrier(0);
    __builtin_amdgcn_s_setprio(1);
    #pragma unroll
    for (int mt = 0; mt < 4; ++mt)
      #pragma unroll
      for (int nt = 0; nt < 4; ++nt)
        acc[mt][nt] = __builtin_amdgcn_mfma_f32_16x16x32_bf16(a[1][mt], b[1][nt], acc[mt][nt], 0, 0, 0);
    __builtin_amdgcn_s_setprio(0);
    asm volatile("s_barrier" ::: "memory");
    if (t + 2 < NT) {
      stage(Ap, (t + 2) * 64, As[t & 1]);
      stage(Bp, (t + 2) * 64, Bs[t & 1]);
    }
  }

  #pragma unroll
  for (int mt = 0; mt < 4; mt++) {
    int row = m0 + wm + mt * 16 + quad * 4;
    #pragma unroll
    for (int nt = 0; nt < 4; nt++) {
      int col = n0 + wn + nt * 16 + l16;
      float bv = bias[col];
      #pragma unroll
      for (int r = 0; r < 4; r++)
        Cout[(uint64_t)(row + r) * N + col] = acc[mt][nt][r] + bv;
    }
  }
}

// ------------------------------------------------------- bucketed attention
#define KSTR 136
__global__ __launch_bounds__(256) void attn_kernel(
    const ushort* __restrict__ Qb, const ushort* __restrict__ Kb,
    const ushort* __restrict__ VT, const int* __restrict__ idxArr,
    const float* __restrict__ wgtArr, ushort* __restrict__ attn_out) {
  __shared__ ushort Qs[64 * KSTR];   // Q, later P
  __shared__ ushort Ks[128 * KSTR];  // K2[j][e], later V2^T[e][j]
  const int blk = blockIdx.x;
  const int u = blk & 63, bh = blk >> 6;
  const int tid = threadIdx.x, wave = tid >> 6, lane = tid & 63;
  const int quad = lane >> 4, l16 = lane & 15;
  const int vu = idxArr[bh * 64 + u] & 63;
  const float w = wgtArr[bh * 64 + u];

  const ushort* Qsrc = Qb + (uint64_t)(bh * 64 + u) * 8192;
  const ushort* Ksrc0 = Kb + (uint64_t)(bh * 64 + vu) * 8192;
  const ushort* Ksrc1 = Kb + (uint64_t)(bh * 64 + u) * 8192;
  const ushort* Vsrc0 = VT + (uint64_t)(bh * 64 + vu) * 8192;
  const ushort* Vsrc1 = VT + (uint64_t)(bh * 64 + u) * 8192;

  for (int g = tid; g < 64 * 16; g += 256) {
    int eb = g & 15, p = g >> 4;
    *(bf16x8*)&Qs[p * KSTR + eb * 8] = *(const bf16x8*)&Qsrc[p * 128 + eb * 8];
  }
  for (int g = tid; g < 128 * 16; g += 256) {
    int eb = g & 15, j = g >> 4;
    const ushort* s = (j < 64) ? &Ksrc0[j * 128 + eb * 8] : &Ksrc1[(j - 64) * 128 + eb * 8];
    *(bf16x8*)&Ks[j * KSTR + eb * 8] = *(const bf16x8*)s;
  }
  __syncthreads();

  f32x4 S[8];
  #pragma unroll
  for (int nt = 0; nt < 8; nt++) S[nt] = (f32x4){0.f, 0.f, 0.f, 0.f};
  #pragma unroll
  for (int kk = 0; kk < 4; kk++) {
    bf16x8 aq = *(const bf16x8*)&Qs[(wave * 16 + l16) * KSTR + kk * 32 + quad * 8];
    #pragma unroll
    for (int nt = 0; nt < 8; nt++) {
      bf16x8 bk = *(const bf16x8*)&Ks[(nt * 16 + l16) * KSTR + kk * 32 + quad * 8];
      S[nt] = __builtin_amdgcn_mfma_f32_16x16x32_bf16(aq, bk, S[nt], 0, 0, 0);
    }
  }
  __syncthreads();  // all waves done reading K2

  // stage V2^T into Ks
  for (int g = tid; g < 128 * 16; g += 256) {
    int jb = g & 15, e = g >> 4;
    const ushort* s = (jb < 8) ? &Vsrc0[e * 64 + jb * 8] : &Vsrc1[e * 64 + (jb - 8) * 8];
    *(bf16x8*)&Ks[e * KSTR + jb * 8] = *(const bf16x8*)s;
  }

  const float scale = 0.03125f;  // (d=1024)^-0.5
  float rowmax[4] = {-1e30f, -1e30f, -1e30f, -1e30f};
  #pragma unroll
  for (int nt = 0; nt < 8; nt++) {
    float cs = scale * ((nt < 4) ? w : 1.0f);
    #pragma unroll
    for (int r = 0; r < 4; r++) {
      S[nt][r] *= cs;
      rowmax[r] = fmaxf(rowmax[r], S[nt][r]);
    }
  }
  #pragma unroll
  for (int off = 1; off < 16; off <<= 1)
    #pragma unroll
    for (int r = 0; r < 4; r++)
      rowmax[r] = fmaxf(rowmax[r], __shfl_xor(rowmax[r], off, 64));
  float rowsum[4] = {0.f, 0.f, 0.f, 0.f};
  #pragma unroll
  for (int nt = 0; nt < 8; nt++)
    #pragma unroll
    for (int r = 0; r < 4; r++) {
      float p = expf(S[nt][r] - rowmax[r]);
      S[nt][r] = p;
      rowsum[r] += p;
    }
  #pragma unroll
  for (int off = 1; off < 16; off <<= 1)
    #pragma unroll
    for (int r = 0; r < 4; r++)
      rowsum[r] += __shfl_xor(rowsum[r], off, 64);
  float rinv[4];
  #pragma unroll
  for (int r = 0; r < 4; r++) rinv[r] = 1.0f / rowsum[r];

  #pragma unroll
  for (int nt = 0; nt < 8; nt++)
    #pragma unroll
    for (int r = 0; r < 4; r++) {
      float pv = S[nt][r] * rinv[r] * ((nt < 4) ? w : 1.0f);
      Qs[(wave * 16 + quad * 4 + r) * KSTR + nt * 16 + l16] = f2b(pv);
    }
  __syncthreads();  // V2^T staged

  f32x4 O[8];
  #pragma unroll
  for (int nt = 0; nt < 8; nt++) O[nt] = (f32x4){0.f, 0.f, 0.f, 0.f};
  #pragma unroll
  for (int kk = 0; kk < 4; kk++) {
    bf16x8 ap = *(const bf16x8*)&Qs[(wave * 16 + l16) * KSTR + kk * 32 + quad * 8];
    #pragma unroll
    for (int nt = 0; nt < 8; nt++) {
      bf16x8 bv = *(const bf16x8*)&Ks[(nt * 16 + l16) * KSTR + kk * 32 + quad * 8];
      O[nt] = __builtin_amdgcn_mfma_f32_16x16x32_bf16(ap, bv, O[nt], 0, 0, 0);
    }
  }

  const int bidx = bh >> 3, head = bh & 7;
  uint64_t rowbase =
      (uint64_t)(bidx * 4096 + u * 64 + wave * 16 + quad * 4) * 1024 + head * 128;
  #pragma unroll
  for (int nt = 0; nt < 8; nt++)
    #pragma unroll
    for (int r = 0; r < 4; r++)
      attn_out[rowbase + (uint64_t)r * 1024 + nt * 16 + l16] = f2b(O[nt][r]);
}

// ---------------------------------------------------------------- launch
extern "C" void kernel_launch(void* const* d_in, const int* in_sizes, int n_in,
                              void* d_out, int out_size, void* d_ws, size_t ws_size,
                              hipStream_t stream) {
  (void)in_sizes; (void)n_in; (void)out_size; (void)ws_size;
  const float* x = (const float*)d_in[0];      // (2,4096,1024) fp32
  const float* gum = (const float*)d_in[1];    // (16,64,64) fp32
  const float* wqkv = (const float*)d_in[2];   // (1024,3072) fp32
  const float* sortw = (const float*)d_in[3];  // (1,8,256,64) fp32
  const float* wout = (const float*)d_in[4];   // (1024,1024) fp32
  const float* bout = (const float*)d_in[5];   // (1024,) fp32
  float* out = (float*)d_out;                  // (2,4096,1024) fp32

  char* ws = (char*)d_ws;
  size_t off = 0;
  auto alloc = [&](size_t bytes) {
    char* p = ws + off;
    off += (bytes + 255) & ~(size_t)255;
    return p;
  };
  ushort* xb = (ushort*)alloc((size_t)8192 * 1024 * 2);
  float* xsum2 = (float*)alloc((size_t)256 * 1024 * 4);
  ushort* wqkvT = (ushort*)alloc((size_t)3072 * 1024 * 2);
  ushort* woutT = (ushort*)alloc((size_t)1024 * 1024 * 2);
  float* SX = (float*)alloc((size_t)16 * 256 * 64 * 4);
  ushort* Qb = (ushort*)alloc((size_t)16 * 64 * 64 * 128 * 2);
  ushort* Kb = (ushort*)alloc((size_t)16 * 64 * 64 * 128 * 2);
  ushort* VT = (ushort*)alloc((size_t)16 * 64 * 128 * 64 * 2);
  int* idxArr = (int*)alloc((size_t)16 * 64 * 4);
  float* wgtArr = (float*)alloc((size_t)16 * 64 * 4);
  ushort* attn = xb;        // alias: xb dead after qkv gemm
  float* SXP = (float*)Qb;  // alias: 8 MB partials, dead before Qb written

  prep_x<<<512, 256, 0, stream>>>(x, xb, xsum2);
  transpose_f2b<<<dim3(3072 / 32, 1024 / 32), 256, 0, stream>>>(wqkv, wqkvT, 1024, 3072);
  transpose_f2b<<<dim3(1024 / 32, 1024 / 32), 256, 0, stream>>>(wout, woutT, 1024, 1024);
  sx_gemm_partial<<<dim3(8, 16, 8), 256, 0, stream>>>(xsum2, wqkv, SXP);
  sx_reduce<<<dim3(8, 128), 256, 0, stream>>>(SXP, SX);
  sortnet_sinkhorn<<<16, 256, 0, stream>>>(SX, sortw, gum, idxArr, wgtArr);
  gemm_qkv<<<dim3(3072 / 128, 8192 / 128), 256, 0, stream>>>(xb, wqkvT, Qb, Kb, VT);
  attn_kernel<<<16 * 64, 256, 0, stream>>>(Qb, Kb, VT, idxArr, wgtArr, attn);
  gemm_out<<<dim3(1024 / 128, 8192 / 128), 256, 0, stream>>>(attn, woutT, bout, out);
}

// Round 12
// 259.190 us; speedup vs baseline: 1.0138x; 1.0138x over previous
//
#include <hip/hip_runtime.h>
#include <stdint.h>

#define TEMP_ 0.75f
#define EPS_ 1e-6f

typedef __attribute__((ext_vector_type(8))) short bf16x8;
typedef __attribute__((ext_vector_type(4))) float f32x4;

typedef __attribute__((address_space(1))) void gvoid_t;
typedef __attribute__((address_space(3))) void lvoid_t;

__device__ __forceinline__ void async_ld16(const void* g, void* l) {
  __builtin_amdgcn_global_load_lds((gvoid_t*)g, (lvoid_t*)l, 16, 0, 0);
}

__device__ __forceinline__ float b2f(ushort u) {
  return __builtin_bit_cast(float, (uint32_t)u << 16);
}
__device__ __forceinline__ ushort f2b(float f) {
  uint32_t x = __builtin_bit_cast(uint32_t, f);
  x += 0x7fffu + ((x >> 16) & 1u);
  return (ushort)(x >> 16);
}

// LDS byte-offset of a __shared__ address (AS3 pointers are 32-bit offsets)
__device__ __forceinline__ uint32_t lds_u32(const void* p) {
  return (uint32_t)(uintptr_t)(lvoid_t*)p;
}

// volatile asm ds_read_b128: all lgkm/vm waiting is explicit (rule 18 discipline).
__device__ __forceinline__ bf16x8 dsr(uint32_t addr) {
  bf16x8 d;
  asm volatile("ds_read_b128 %0, %1" : "=v"(d) : "v"(addr));
  return d;
}

// ------------------------------------------------------- prep_x: fp32 x -> bf16 xb + fp32 half-bucket sums
// 512 blocks (column-split): 2 blocks/CU for TLP; per-column serial sum order unchanged (bitwise).
__global__ __launch_bounds__(256) void prep_x(
    const float* __restrict__ x, ushort* __restrict__ xb, float* __restrict__ xsum2) {
  const int hb = blockIdx.x >> 1;   // half-bucket index (old blk), 0..255
  const int ch = blockIdx.x & 1;    // column half
  const int bu = hb >> 1, half = hb & 1;
  const int b = bu >> 6, u = bu & 63;
  const int c = ch * 512 + threadIdx.x * 2;
  const float* src = x + ((size_t)(b * 4096 + u * 64 + half * 32)) * 1024 + c;
  ushort* dst = xb + ((size_t)(b * 4096 + u * 64 + half * 32)) * 1024 + c;
  float s0 = 0.f, s1 = 0.f;
  #pragma unroll 4
  for (int pos = 0; pos < 32; pos++) {
    float2 v = *(const float2*)(src + (size_t)pos * 1024);
    s0 += v.x; s1 += v.y;
    ushort2 o;
    o.x = f2b(v.x); o.y = f2b(v.y);
    *(ushort2*)(dst + (size_t)pos * 1024) = o;
  }
  float2 sv = {s0, s1};
  *(float2*)&xsum2[(size_t)hb * 1024 + c] = sv;
}

// ------------------------------------------------------- transpose + fp32->bf16
__global__ __launch_bounds__(256) void transpose_f2b(
    const float* __restrict__ src, ushort* __restrict__ dst, int R, int C) {
  __shared__ float tile[32][33];
  int bx = blockIdx.x * 32;
  int by = blockIdx.y * 32;
  int tx = threadIdx.x & 31, ty = threadIdx.x >> 5;  // 32 x 8
  #pragma unroll
  for (int i = 0; i < 32; i += 8)
    tile[ty + i][tx] = src[(size_t)(by + ty + i) * C + bx + tx];
  __syncthreads();
  #pragma unroll
  for (int i = 0; i < 32; i += 8)
    dst[(size_t)(bx + ty + i) * R + by + tx] = f2b(tile[tx][ty + i]);
}

// ------------------------------------------------------- sx partial: split-K over 8 chunks
// SXP[kc*128 + bu][n]  (n in [0,2048)); unroll 4 for load ILP (per-acc fp order unchanged)
__global__ __launch_bounds__(256) void sx_gemm_partial(
    const float* __restrict__ xsum2, const float* __restrict__ wqkv,
    float* __restrict__ SXP) {
  __shared__ float xs[128 * 8];  // k-major: xs[k*8 + r]
  const int cb = blockIdx.x;  // 8 colblocks of 256 n
  const int rt = blockIdx.y;  // 16 rowtiles of 8 bu
  const int kc = blockIdx.z;  // 8 k-chunks of 128
  const int tid = threadIdx.x;
  for (int idx = tid; idx < 1024; idx += 256) {
    int k = idx >> 3, r = idx & 7;
    int bu = rt * 8 + r;
    int kk = kc * 128 + k;
    xs[idx] = xsum2[(size_t)(bu * 2) * 1024 + kk] + xsum2[(size_t)(bu * 2 + 1) * 1024 + kk];
  }
  __syncthreads();
  const int n = cb * 256 + tid;
  float acc[8];
  #pragma unroll
  for (int r = 0; r < 8; r++) acc[r] = 0.f;
  #pragma unroll 4
  for (int k = 0; k < 128; k++) {
    float w = wqkv[(size_t)(kc * 128 + k) * 3072 + n];
    float4 a0 = *(const float4*)&xs[k * 8];
    float4 a1 = *(const float4*)&xs[k * 8 + 4];
    acc[0] += a0.x * w; acc[1] += a0.y * w; acc[2] += a0.z * w; acc[3] += a0.w * w;
    acc[4] += a1.x * w; acc[5] += a1.y * w; acc[6] += a1.z * w; acc[7] += a1.w * w;
  }
  #pragma unroll
  for (int r = 0; r < 8; r++)
    SXP[(size_t)(kc * 128 + rt * 8 + r) * 2048 + n] = acc[r];
}

// ------------------------------------------------------- sx reduce: fixed-order sum + scatter
// SX layout: [bh][e2(256)][u(64)]
__global__ __launch_bounds__(256) void sx_reduce(
    const float* __restrict__ SXP, float* __restrict__ SX) {
  const int bu = blockIdx.y;
  const int n = blockIdx.x * 256 + threadIdx.x;
  float s = 0.f;
  #pragma unroll
  for (int kc = 0; kc < 8; kc++)
    s += SXP[(size_t)(kc * 128 + bu) * 2048 + n];
  const int head = (n >> 7) & 7;
  const int e2 = ((n >> 10) << 7) | (n & 127);
  const int b = bu >> 6, u = bu & 63;
  SX[((size_t)((b * 8 + head) * 256) + e2) * 64 + u] = s;
}

// ------------------------------------------------------- sortnet + sinkhorn + top1 (fp32, LDS-staged)
// Sinkhorn reductions via 4-adjacent-lane shuffles (bitwise-identical combine order).
__global__ __launch_bounds__(256) void sortnet_sinkhorn(
    const float* __restrict__ SX, const float* __restrict__ sortw,
    const float* __restrict__ gum, int* __restrict__ idxArr,
    float* __restrict__ wgtArr) {
  __shared__ float sxl[64 * 64];  // chunk: [e][u]  16 KB
  __shared__ float wl[64 * 64];   // chunk: [e][c]  16 KB
  __shared__ float rr[64 * 65];   // 16.6 KB
  const int bh = blockIdx.x, tid = threadIdx.x, head = bh & 7;
  const int ui = tid & 15, ci = tid >> 4;  // 4x4 tile position

  float acc[4][4];
  #pragma unroll
  for (int i = 0; i < 4; i++)
    #pragma unroll
    for (int j = 0; j < 4; j++) acc[i][j] = 0.f;

  const f32x4* SX4 = (const f32x4*)(SX + (size_t)bh * 16384);
  const f32x4* W4 = (const f32x4*)(sortw + (size_t)head * 16384);
  f32x4* sxl4 = (f32x4*)sxl;
  f32x4* wl4 = (f32x4*)wl;

  #pragma unroll 1
  for (int ch = 0; ch < 4; ch++) {
    __syncthreads();
    #pragma unroll 1
    for (int g = tid; g < 1024; g += 256) {
      sxl4[g] = SX4[ch * 1024 + g];
      wl4[g] = W4[ch * 1024 + g];
    }
    __syncthreads();
    #pragma unroll 2
    for (int e = 0; e < 64; e++) {
      f32x4 a = sxl4[e * 16 + ui];
      f32x4 w = wl4[e * 16 + ci];
      #pragma unroll
      for (int i = 0; i < 4; i++)
        #pragma unroll
        for (int j = 0; j < 4; j++) acc[i][j] += a[i] * w[j];
    }
  }

  // leaky relu + gumbel + log -> rr
  #pragma unroll
  for (int i = 0; i < 4; i++)
    #pragma unroll
    for (int j = 0; j < 4; j++) {
      int u = ui * 4 + i, c = ci * 4 + j;
      float dot = acc[i][j];
      float r0 = dot > 0.f ? dot : 0.01f * dot;
      float gu = gum[(size_t)bh * 4096 + u * 64 + c];
      float inner = -logf(gu + EPS_) + EPS_;
      float g = -logf(fmaxf(inner, 1e-38f));
      rr[u * 65 + c] = (logf(fmaxf(r0 + EPS_, EPS_)) + g) / TEMP_;
    }
  __syncthreads();

  // 4 adjacent lanes own one row (row norm) / one col (col norm); qq = quarter.
  const int row4 = tid >> 2, qq = tid & 3;
  #pragma unroll 1
  for (int it = 0; it < 5; it++) {
    {  // row norm (axis c)
      float pm = -1e30f;
      #pragma unroll
      for (int j = 0; j < 16; j++) pm = fmaxf(pm, rr[row4 * 65 + qq * 16 + j]);
      float m0 = __shfl(pm, 0, 4), m1 = __shfl(pm, 1, 4);
      float m2 = __shfl(pm, 2, 4), m3 = __shfl(pm, 3, 4);
      float m = fmaxf(fmaxf(m0, m1), fmaxf(m2, m3));
      float ps = 0.f;
      #pragma unroll
      for (int j = 0; j < 16; j++) ps += expf(rr[row4 * 65 + qq * 16 + j] - m);
      float s0 = __shfl(ps, 0, 4), s1 = __shfl(ps, 1, 4);
      float s2 = __shfl(ps, 2, 4), s3 = __shfl(ps, 3, 4);
      float l = m + logf(((s0 + s1) + s2) + s3);
      #pragma unroll
      for (int j = 0; j < 16; j++) rr[row4 * 65 + qq * 16 + j] -= l;
      __syncthreads();
    }
    {  // col norm (axis u)
      float pm = -1e30f;
      #pragma unroll
      for (int j = 0; j < 16; j++) pm = fmaxf(pm, rr[(qq * 16 + j) * 65 + row4]);
      float m0 = __shfl(pm, 0, 4), m1 = __shfl(pm, 1, 4);
      float m2 = __shfl(pm, 2, 4), m3 = __shfl(pm, 3, 4);
      float m = fmaxf(fmaxf(m0, m1), fmaxf(m2, m3));
      float ps = 0.f;
      #pragma unroll
      for (int j = 0; j < 16; j++) ps += expf(rr[(qq * 16 + j) * 65 + row4] - m);
      float s0 = __shfl(ps, 0, 4), s1 = __shfl(ps, 1, 4);
      float s2 = __shfl(ps, 2, 4), s3 = __shfl(ps, 3, 4);
      float l = m + logf(((s0 + s1) + s2) + s3);
      #pragma unroll
      for (int j = 0; j < 16; j++) rr[(qq * 16 + j) * 65 + row4] -= l;
      __syncthreads();
    }
  }

  {  // first-max argmax over cols (np semantics): per-quarter scan then q-ascending strict >
    float pv = -1e30f;
    int pi = 0;
    #pragma unroll
    for (int j = 0; j < 16; j++) {
      float v = rr[row4 * 65 + qq * 16 + j];
      if (v > pv) { pv = v; pi = qq * 16 + j; }
    }
    float v0 = __shfl(pv, 0, 4); int i0 = __shfl(pi, 0, 4);
    float v1 = __shfl(pv, 1, 4); int i1 = __shfl(pi, 1, 4);
    float v2 = __shfl(pv, 2, 4); int i2 = __shfl(pi, 2, 4);
    float v3 = __shfl(pv, 3, 4); int i3 = __shfl(pi, 3, 4);
    float best = -1e30f;
    int bi = 0;
    if (v0 > best) { best = v0; bi = i0; }
    if (v1 > best) { best = v1; bi = i1; }
    if (v2 > best) { best = v2; bi = i2; }
    if (v3 > best) { best = v3; bi = i3; }
    if (qq == 0) {
      idxArr[bh * 64 + row4] = bi;
      wgtArr[bh * 64 + row4] = expf(fminf(best, 80.f));
    }
  }
}

// ------------------------------------------------------- QKV GEMM: r8 schedule + by-fastest
// XCD chunk traversal (B-panel 256KB reused by 8 consecutive same-XCD blocks; chunk's 8 A
// panels = 2MB stay L2-resident). Bijective: by <-> (xcd, c&7), bx <-> c>>3.
__global__ __launch_bounds__(256, 2) void gemm_qkv(
    const ushort* __restrict__ A, const ushort* __restrict__ BT,
    ushort* __restrict__ Qb, ushort* __restrict__ Kb, ushort* __restrict__ VT) {
  const int K = 1024;
  __shared__ ushort As[2][128 * 64];
  __shared__ ushort Bs[2][128 * 64];
  const int tid = threadIdx.x;
  const int wave = tid >> 6, lane = tid & 63;
  const int quad = lane >> 4, l16 = lane & 15;
  const int gx = gridDim.x;
  const int lin = blockIdx.y * gx + blockIdx.x;
  const int xcd = lin & 7, c = lin >> 3;  // dispatch-linear -> XCD, chunk-local index
  const int by = xcd * 8 + (c & 7);       // by-fastest within chunk
  const int bx = c >> 3;
  const int m0 = by * 128, n0 = bx * 128;
  const int wm = (wave >> 1) * 64, wn = (wave & 1) * 64;
  const ushort* Ap = A + (uint64_t)m0 * K;
  const ushort* Bp = BT + (uint64_t)n0 * K;

  auto stage = [&](const ushort* G, int k0, ushort* buf) {
    #pragma unroll
    for (int q = 0; q < 4; ++q) {
      int p = q * 256 + tid;
      int row = p >> 3, pp = p & 7;
      int cc = pp ^ (row & 7);
      async_ld16(G + (uint64_t)row * K + k0 + cc * 8,
                 buf + (q * 256 + wave * 64) * 8);
    }
  };

  const uint32_t asB = lds_u32(&As[0][0]);
  const uint32_t bsB = lds_u32(&Bs[0][0]);
  uint32_t aoff[2][4], boff[2][4];
  #pragma unroll
  for (int kk = 0; kk < 2; ++kk) {
    int pc = (kk * 4 + quad) ^ (l16 & 7);
    #pragma unroll
    for (int mt = 0; mt < 4; ++mt) {
      aoff[kk][mt] = (uint32_t)((wm + mt * 16 + l16) * 128 + pc * 16);
      boff[kk][mt] = (uint32_t)((wn + mt * 16 + l16) * 128 + pc * 16);
    }
  }

  f32x4 acc[4][4];
  #pragma unroll
  for (int i = 0; i < 4; i++)
    #pragma unroll
    for (int j = 0; j < 4; j++) acc[i][j] = (f32x4){0.f, 0.f, 0.f, 0.f};

  const int NT = K >> 6;  // 16
  stage(Ap, 0, As[0]);
  stage(Bp, 0, Bs[0]);
  stage(Ap, 64, As[1]);
  stage(Bp, 64, Bs[1]);

  #pragma unroll 1
  for (int t = 0; t < NT; ++t) {
    if (t < NT - 1)
      asm volatile("s_waitcnt vmcnt(8)\n\ts_barrier" ::: "memory");
    else
      asm volatile("s_waitcnt vmcnt(0)\n\ts_barrier" ::: "memory");

    const uint32_t ab = asB + (uint32_t)(t & 1) * 16384u;
    const uint32_t bb = bsB + (uint32_t)(t & 1) * 16384u;
    bf16x8 a[2][4], b[2][4];
    #pragma unroll
    for (int kk = 0; kk < 2; ++kk) {
      #pragma unroll
      for (int mt = 0; mt < 4; ++mt) a[kk][mt] = dsr(ab + aoff[kk][mt]);
      #pragma unroll
      for (int nt = 0; nt < 4; ++nt) b[kk][nt] = dsr(bb + boff[kk][nt]);
    }
    asm volatile("s_waitcnt lgkmcnt(8)" ::: "memory");
    __builtin_amdgcn_sched_barrier(0);
    __builtin_amdgcn_s_setprio(1);
    #pragma unroll
    for (int mt = 0; mt < 4; ++mt)
      #pragma unroll
      for (int nt = 0; nt < 4; ++nt)
        acc[mt][nt] = __builtin_amdgcn_mfma_f32_16x16x32_bf16(a[0][mt], b[0][nt], acc[mt][nt], 0, 0, 0);
    __builtin_amdgcn_s_setprio(0);
    asm volatile("s_waitcnt lgkmcnt(0)" ::: "memory");
    __builtin_amdgcn_sched_barrier(0);
    __builtin_amdgcn_s_setprio(1);
    #pragma unroll
    for (int mt = 0; mt < 4; ++mt)
      #pragma unroll
      for (int nt = 0; nt < 4; ++nt)
        acc[mt][nt] = __builtin_amdgcn_mfma_f32_16x16x32_bf16(a[1][mt], b[1][nt], acc[mt][nt], 0, 0, 0);
    __builtin_amdgcn_s_setprio(0);
    asm volatile("s_barrier" ::: "memory");
    if (t + 2 < NT) {
      stage(Ap, (t + 2) * 64, As[t & 1]);
      stage(Bp, (t + 2) * 64, Bs[t & 1]);
    }
  }

  int which = bx >> 3;  // 0=q,1=k,2=v  (n0 multiple of 128)
  int head = bx & 7;
  #pragma unroll
  for (int mt = 0; mt < 4; mt++) {
    int mrow = m0 + wm + mt * 16 + quad * 4;
    int bidx = mrow >> 12;
    int ttok = mrow & 4095;
    int u = ttok >> 6, pos = ttok & 63;
    int bh = bidx * 8 + head;
    #pragma unroll
    for (int nt = 0; nt < 4; nt++) {
      int e = wn + nt * 16 + l16;
      if (which == 2) {
        ushort4 pk;
        pk.x = f2b(acc[mt][nt][0]);
        pk.y = f2b(acc[mt][nt][1]);
        pk.z = f2b(acc[mt][nt][2]);
        pk.w = f2b(acc[mt][nt][3]);
        *(ushort4*)&VT[((uint64_t)(bh * 64 + u) * 128 + e) * 64 + pos] = pk;
      } else {
        ushort* dst = (which == 0) ? Qb : Kb;
        #pragma unroll
        for (int r = 0; r < 4; r++)
          dst[((uint64_t)(bh * 64 + u) * 64 + pos + r) * 128 + e] = f2b(acc[mt][nt][r]);
      }
    }
  }
}

// ------------------------------------------------------- out-proj GEMM: exact clone of the
// validated gemm_qkv loop (counted vmcnt + split lgkm + T2 swizzle + XCD swizzle + setprio,
// K=1024 folded), with the mode-0 bias epilogue. M=8192, N=1024 -> grid (8,64), nwg%8==0.
__global__ __launch_bounds__(256, 2) void gemm_out(
    const ushort* __restrict__ A, const ushort* __restrict__ BT,
    const float* __restrict__ bias, float* __restrict__ Cout) {
  const int K = 1024, N = 1024;
  __shared__ ushort As[2][128 * 64];
  __shared__ ushort Bs[2][128 * 64];
  const int tid = threadIdx.x;
  const int wave = tid >> 6, lane = tid & 63;
  const int quad = lane >> 4, l16 = lane & 15;
  const int gx = gridDim.x;
  const int lin = blockIdx.y * gx + blockIdx.x;
  const int nwg = gx * gridDim.y;
  const int swz = (lin & 7) * (nwg >> 3) + (lin >> 3);
  const int bx = swz % gx, by = swz / gx;
  const int m0 = by * 128, n0 = bx * 128;
  const int wm = (wave >> 1) * 64, wn = (wave & 1) * 64;
  const ushort* Ap = A + (uint64_t)m0 * K;
  const ushort* Bp = BT + (uint64_t)n0 * K;

  auto stage = [&](const ushort* G, int k0, ushort* buf) {
    #pragma unroll
    for (int q = 0; q < 4; ++q) {
      int p = q * 256 + tid;
      int row = p >> 3, pp = p & 7;
      int cc = pp ^ (row & 7);
      async_ld16(G + (uint64_t)row * K + k0 + cc * 8,
                 buf + (q * 256 + wave * 64) * 8);
    }
  };

  const uint32_t asB = lds_u32(&As[0][0]);
  const uint32_t bsB = lds_u32(&Bs[0][0]);
  uint32_t aoff[2][4], boff[2][4];
  #pragma unroll
  for (int kk = 0; kk < 2; ++kk) {
    int pc = (kk * 4 + quad) ^ (l16 & 7);
    #pragma unroll
    for (int mt = 0; mt < 4; ++mt) {
      aoff[kk][mt] = (uint32_t)((wm + mt * 16 + l16) * 128 + pc * 16);
      boff[kk][mt] = (uint32_t)((wn + mt * 16 + l16) * 128 + pc * 16);
    }
  }

  f32x4 acc[4][4];
  #pragma unroll
  for (int i = 0; i < 4; i++)
    #pragma unroll
    for (int j = 0; j < 4; j++) acc[i][j] = (f32x4){0.f, 0.f, 0.f, 0.f};

  const int NT = K >> 6;  // 16
  stage(Ap, 0, As[0]);
  stage(Bp, 0, Bs[0]);
  stage(Ap, 64, As[1]);
  stage(Bp, 64, Bs[1]);

  #pragma unroll 1
  for (int t = 0; t < NT; ++t) {
    if (t < NT - 1)
      asm volatile("s_waitcnt vmcnt(8)\n\ts_barrier" ::: "memory");
    else
      asm volatile("s_waitcnt vmcnt(0)\n\ts_barrier" ::: "memory");

    const uint32_t ab = asB + (uint32_t)(t & 1) * 16384u;
    const uint32_t bb = bsB + (uint32_t)(t & 1) * 16384u;
    bf16x8 a[2][4], b[2][4];
    #pragma unroll
    for (int kk = 0; kk < 2; ++kk) {
      #pragma unroll
      for (int mt = 0; mt < 4; ++mt) a[kk][mt] = dsr(ab + aoff[kk][mt]);
      #pragma unroll
      for (int nt = 0; nt < 4; ++nt) b[kk][nt] = dsr(bb + boff[kk][nt]);
    }
    asm volatile("s_waitcnt lgkmcnt(8)" ::: "memory");
    __builtin_amdgcn_sched_barrier(0);
    __builtin_amdgcn_s_setprio(1);
    #pragma unroll
    for (int mt = 0; mt < 4; ++mt)
      #pragma unroll
      for (int nt = 0; nt < 4; ++nt)
        acc[mt][nt] = __builtin_amdgcn_mfma_f32_16x16x32_bf16(a[0][mt], b[0][nt], acc[mt][nt], 0, 0, 0);
    __builtin_amdgcn_s_setprio(0);
    asm volatile("s_waitcnt lgkmcnt(0)" ::: "memory");
    __builtin_amdgcn_sched_barrier(0);
    __builtin_amdgcn_s_setprio(1);
    #pragma unroll
    for (int mt = 0; mt < 4; ++mt)
      #pragma unroll
      for (int nt = 0; nt < 4; ++nt)
        acc[mt][nt] = __builtin_amdgcn_mfma_f32_16x16x32_bf16(a[1][mt], b[1][nt], acc[mt][nt], 0, 0, 0);
    __builtin_amdgcn_s_setprio(0);
    asm volatile("s_barrier" ::: "memory");
    if (t + 2 < NT) {
      stage(Ap, (t + 2) * 64, As[t & 1]);
      stage(Bp, (t + 2) * 64, Bs[t & 1]);
    }
  }

  #pragma unroll
  for (int mt = 0; mt < 4; mt++) {
    int row = m0 + wm + mt * 16 + quad * 4;
    #pragma unroll
    for (int nt = 0; nt < 4; nt++) {
      int col = n0 + wn + nt * 16 + l16;
      float bv = bias[col];
      #pragma unroll
      for (int r = 0; r < 4; r++)
        Cout[(uint64_t)(row + r) * N + col] = acc[mt][nt][r] + bv;
    }
  }
}

// ------------------------------------------------------- bucketed attention
#define KSTR 136
__global__ __launch_bounds__(256) void attn_kernel(
    const ushort* __restrict__ Qb, const ushort* __restrict__ Kb,
    const ushort* __restrict__ VT, const int* __restrict__ idxArr,
    const float* __restrict__ wgtArr, ushort* __restrict__ attn_out) {
  __shared__ ushort Qs[64 * KSTR];   // Q, later P
  __shared__ ushort Ks[128 * KSTR];  // K2[j][e], later V2^T[e][j]
  const int blk = blockIdx.x;
  const int u = blk & 63, bh = blk >> 6;
  const int tid = threadIdx.x, wave = tid >> 6, lane = tid & 63;
  const int quad = lane >> 4, l16 = lane & 15;
  const int vu = idxArr[bh * 64 + u] & 63;
  const float w = wgtArr[bh * 64 + u];

  const ushort* Qsrc = Qb + (uint64_t)(bh * 64 + u) * 8192;
  const ushort* Ksrc0 = Kb + (uint64_t)(bh * 64 + vu) * 8192;
  const ushort* Ksrc1 = Kb + (uint64_t)(bh * 64 + u) * 8192;
  const ushort* Vsrc0 = VT + (uint64_t)(bh * 64 + vu) * 8192;
  const ushort* Vsrc1 = VT + (uint64_t)(bh * 64 + u) * 8192;

  for (int g = tid; g < 64 * 16; g += 256) {
    int eb = g & 15, p = g >> 4;
    *(bf16x8*)&Qs[p * KSTR + eb * 8] = *(const bf16x8*)&Qsrc[p * 128 + eb * 8];
  }
  for (int g = tid; g < 128 * 16; g += 256) {
    int eb = g & 15, j = g >> 4;
    const ushort* s = (j < 64) ? &Ksrc0[j * 128 + eb * 8] : &Ksrc1[(j - 64) * 128 + eb * 8];
    *(bf16x8*)&Ks[j * KSTR + eb * 8] = *(const bf16x8*)s;
  }
  __syncthreads();

  f32x4 S[8];
  #pragma unroll
  for (int nt = 0; nt < 8; nt++) S[nt] = (f32x4){0.f, 0.f, 0.f, 0.f};
  #pragma unroll
  for (int kk = 0; kk < 4; kk++) {
    bf16x8 aq = *(const bf16x8*)&Qs[(wave * 16 + l16) * KSTR + kk * 32 + quad * 8];
    #pragma unroll
    for (int nt = 0; nt < 8; nt++) {
      bf16x8 bk = *(const bf16x8*)&Ks[(nt * 16 + l16) * KSTR + kk * 32 + quad * 8];
      S[nt] = __builtin_amdgcn_mfma_f32_16x16x32_bf16(aq, bk, S[nt], 0, 0, 0);
    }
  }
  __syncthreads();  // all waves done reading K2

  // stage V2^T into Ks
  for (int g = tid; g < 128 * 16; g += 256) {
    int jb = g & 15, e = g >> 4;
    const ushort* s = (jb < 8) ? &Vsrc0[e * 64 + jb * 8] : &Vsrc1[e * 64 + (jb - 8) * 8];
    *(bf16x8*)&Ks[e * KSTR + jb * 8] = *(const bf16x8*)s;
  }

  const float scale = 0.03125f;  // (d=1024)^-0.5
  float rowmax[4] = {-1e30f, -1e30f, -1e30f, -1e30f};
  #pragma unroll
  for (int nt = 0; nt < 8; nt++) {
    float cs = scale * ((nt < 4) ? w : 1.0f);
    #pragma unroll
    for (int r = 0; r < 4; r++) {
      S[nt][r] *= cs;
      rowmax[r] = fmaxf(rowmax[r], S[nt][r]);
    }
  }
  #pragma unroll
  for (int off = 1; off < 16; off <<= 1)
    #pragma unroll
    for (int r = 0; r < 4; r++)
      rowmax[r] = fmaxf(rowmax[r], __shfl_xor(rowmax[r], off, 64));
  float rowsum[4] = {0.f, 0.f, 0.f, 0.f};
  #pragma unroll
  for (int nt = 0; nt < 8; nt++)
    #pragma unroll
    for (int r = 0; r < 4; r++) {
      float p = expf(S[nt][r] - rowmax[r]);
      S[nt][r] = p;
      rowsum[r] += p;
    }
  #pragma unroll
  for (int off = 1; off < 16; off <<= 1)
    #pragma unroll
    for (int r = 0; r < 4; r++)
      rowsum[r] += __shfl_xor(rowsum[r], off, 64);
  float rinv[4];
  #pragma unroll
  for (int r = 0; r < 4; r++) rinv[r] = 1.0f / rowsum[r];

  #pragma unroll
  for (int nt = 0; nt < 8; nt++)
    #pragma unroll
    for (int r = 0; r < 4; r++) {
      float pv = S[nt][r] * rinv[r] * ((nt < 4) ? w : 1.0f);
      Qs[(wave * 16 + quad * 4 + r) * KSTR + nt * 16 + l16] = f2b(pv);
    }
  __syncthreads();  // V2^T staged

  f32x4 O[8];
  #pragma unroll
  for (int nt = 0; nt < 8; nt++) O[nt] = (f32x4){0.f, 0.f, 0.f, 0.f};
  #pragma unroll
  for (int kk = 0; kk < 4; kk++) {
    bf16x8 ap = *(const bf16x8*)&Qs[(wave * 16 + l16) * KSTR + kk * 32 + quad * 8];
    #pragma unroll
    for (int nt = 0; nt < 8; nt++) {
      bf16x8 bv = *(const bf16x8*)&Ks[(nt * 16 + l16) * KSTR + kk * 32 + quad * 8];
      O[nt] = __builtin_amdgcn_mfma_f32_16x16x32_bf16(ap, bv, O[nt], 0, 0, 0);
    }
  }

  const int bidx = bh >> 3, head = bh & 7;
  uint64_t rowbase =
      (uint64_t)(bidx * 4096 + u * 64 + wave * 16 + quad * 4) * 1024 + head * 128;
  #pragma unroll
  for (int nt = 0; nt < 8; nt++)
    #pragma unroll
    for (int r = 0; r < 4; r++)
      attn_out[rowbase + (uint64_t)r * 1024 + nt * 16 + l16] = f2b(O[nt][r]);
}

// ---------------------------------------------------------------- launch
extern "C" void kernel_launch(void* const* d_in, const int* in_sizes, int n_in,
                              void* d_out, int out_size, void* d_ws, size_t ws_size,
                              hipStream_t stream) {
  (void)in_sizes; (void)n_in; (void)out_size; (void)ws_size;
  const float* x = (const float*)d_in[0];      // (2,4096,1024) fp32
  const float* gum = (const float*)d_in[1];    // (16,64,64) fp32
  const float* wqkv = (const float*)d_in[2];   // (1024,3072) fp32
  const float* sortw = (const float*)d_in[3];  // (1,8,256,64) fp32
  const float* wout = (const float*)d_in[4];   // (1024,1024) fp32
  const float* bout = (const float*)d_in[5];   // (1024,) fp32
  float* out = (float*)d_out;                  // (2,4096,1024) fp32

  char* ws = (char*)d_ws;
  size_t off = 0;
  auto alloc = [&](size_t bytes) {
    char* p = ws + off;
    off += (bytes + 255) & ~(size_t)255;
    return p;
  };
  ushort* xb = (ushort*)alloc((size_t)8192 * 1024 * 2);
  float* xsum2 = (float*)alloc((size_t)256 * 1024 * 4);
  ushort* wqkvT = (ushort*)alloc((size_t)3072 * 1024 * 2);
  ushort* woutT = (ushort*)alloc((size_t)1024 * 1024 * 2);
  float* SX = (float*)alloc((size_t)16 * 256 * 64 * 4);
  ushort* Qb = (ushort*)alloc((size_t)16 * 64 * 64 * 128 * 2);
  ushort* Kb = (ushort*)alloc((size_t)16 * 64 * 64 * 128 * 2);
  ushort* VT = (ushort*)alloc((size_t)16 * 64 * 128 * 64 * 2);
  int* idxArr = (int*)alloc((size_t)16 * 64 * 4);
  float* wgtArr = (float*)alloc((size_t)16 * 64 * 4);
  ushort* attn = xb;        // alias: xb dead after qkv gemm
  float* SXP = (float*)Qb;  // alias: 8 MB partials, dead before Qb written

  prep_x<<<512, 256, 0, stream>>>(x, xb, xsum2);
  transpose_f2b<<<dim3(3072 / 32, 1024 / 32), 256, 0, stream>>>(wqkv, wqkvT, 1024, 3072);
  transpose_f2b<<<dim3(1024 / 32, 1024 / 32), 256, 0, stream>>>(wout, woutT, 1024, 1024);
  sx_gemm_partial<<<dim3(8, 16, 8), 256, 0, stream>>>(xsum2, wqkv, SXP);
  sx_reduce<<<dim3(8, 128), 256, 0, stream>>>(SXP, SX);
  sortnet_sinkhorn<<<16, 256, 0, stream>>>(SX, sortw, gum, idxArr, wgtArr);
  gemm_qkv<<<dim3(3072 / 128, 8192 / 128), 256, 0, stream>>>(xb, wqkvT, Qb, Kb, VT);
  attn_kernel<<<16 * 64, 256, 0, stream>>>(Qb, Kb, VT, idxArr, wgtArr, attn);
  gemm_out<<<dim3(1024 / 128, 8192 / 128), 256, 0, stream>>>(attn, woutT, bout, out);
}

// Round 13
// 247.774 us; speedup vs baseline: 1.0605x; 1.0461x over previous
//
#include <hip/hip_runtime.h>
#include <stdint.h>

#define TEMP_ 0.75f
#define EPS_ 1e-6f

typedef __attribute__((ext_vector_type(8))) short bf16x8;
typedef __attribute__((ext_vector_type(4))) float f32x4;

typedef __attribute__((address_space(1))) void gvoid_t;
typedef __attribute__((address_space(3))) void lvoid_t;

__device__ __forceinline__ void async_ld16(const void* g, void* l) {
  __builtin_amdgcn_global_load_lds((gvoid_t*)g, (lvoid_t*)l, 16, 0, 0);
}

__device__ __forceinline__ float b2f(ushort u) {
  return __builtin_bit_cast(float, (uint32_t)u << 16);
}
__device__ __forceinline__ ushort f2b(float f) {
  uint32_t x = __builtin_bit_cast(uint32_t, f);
  x += 0x7fffu + ((x >> 16) & 1u);
  return (ushort)(x >> 16);
}

// LDS byte-offset of a __shared__ address (AS3 pointers are 32-bit offsets)
__device__ __forceinline__ uint32_t lds_u32(const void* p) {
  return (uint32_t)(uintptr_t)(lvoid_t*)p;
}

// volatile asm ds_read_b128: all lgkm/vm waiting is explicit (rule 18 discipline).
__device__ __forceinline__ bf16x8 dsr(uint32_t addr) {
  bf16x8 d;
  asm volatile("ds_read_b128 %0, %1" : "=v"(d) : "v"(addr));
  return d;
}

// ------------------------------------------------------- prep_x: fp32 x -> bf16 xb + fp32 half-bucket sums
// 512 blocks (column-split): 2 blocks/CU for TLP; per-column serial sum order unchanged (bitwise).
__global__ __launch_bounds__(256) void prep_x(
    const float* __restrict__ x, ushort* __restrict__ xb, float* __restrict__ xsum2) {
  const int hb = blockIdx.x >> 1;   // half-bucket index (old blk), 0..255
  const int ch = blockIdx.x & 1;    // column half
  const int bu = hb >> 1, half = hb & 1;
  const int b = bu >> 6, u = bu & 63;
  const int c = ch * 512 + threadIdx.x * 2;
  const float* src = x + ((size_t)(b * 4096 + u * 64 + half * 32)) * 1024 + c;
  ushort* dst = xb + ((size_t)(b * 4096 + u * 64 + half * 32)) * 1024 + c;
  float s0 = 0.f, s1 = 0.f;
  #pragma unroll 4
  for (int pos = 0; pos < 32; pos++) {
    float2 v = *(const float2*)(src + (size_t)pos * 1024);
    s0 += v.x; s1 += v.y;
    ushort2 o;
    o.x = f2b(v.x); o.y = f2b(v.y);
    *(ushort2*)(dst + (size_t)pos * 1024) = o;
  }
  float2 sv = {s0, s1};
  *(float2*)&xsum2[(size_t)hb * 1024 + c] = sv;
}

// ------------------------------------------------------- transpose + fp32->bf16
__global__ __launch_bounds__(256) void transpose_f2b(
    const float* __restrict__ src, ushort* __restrict__ dst, int R, int C) {
  __shared__ float tile[32][33];
  int bx = blockIdx.x * 32;
  int by = blockIdx.y * 32;
  int tx = threadIdx.x & 31, ty = threadIdx.x >> 5;  // 32 x 8
  #pragma unroll
  for (int i = 0; i < 32; i += 8)
    tile[ty + i][tx] = src[(size_t)(by + ty + i) * C + bx + tx];
  __syncthreads();
  #pragma unroll
  for (int i = 0; i < 32; i += 8)
    dst[(size_t)(bx + ty + i) * R + by + tx] = f2b(tile[tx][ty + i]);
}

// ------------------------------------------------------- sx partial: split-K over 8 chunks
// SXP[kc*128 + bu][n]  (n in [0,2048)); unroll 4 for load ILP (per-acc fp order unchanged)
__global__ __launch_bounds__(256) void sx_gemm_partial(
    const float* __restrict__ xsum2, const float* __restrict__ wqkv,
    float* __restrict__ SXP) {
  __shared__ float xs[128 * 8];  // k-major: xs[k*8 + r]
  const int cb = blockIdx.x;  // 8 colblocks of 256 n
  const int rt = blockIdx.y;  // 16 rowtiles of 8 bu
  const int kc = blockIdx.z;  // 8 k-chunks of 128
  const int tid = threadIdx.x;
  for (int idx = tid; idx < 1024; idx += 256) {
    int k = idx >> 3, r = idx & 7;
    int bu = rt * 8 + r;
    int kk = kc * 128 + k;
    xs[idx] = xsum2[(size_t)(bu * 2) * 1024 + kk] + xsum2[(size_t)(bu * 2 + 1) * 1024 + kk];
  }
  __syncthreads();
  const int n = cb * 256 + tid;
  float acc[8];
  #pragma unroll
  for (int r = 0; r < 8; r++) acc[r] = 0.f;
  #pragma unroll 4
  for (int k = 0; k < 128; k++) {
    float w = wqkv[(size_t)(kc * 128 + k) * 3072 + n];
    float4 a0 = *(const float4*)&xs[k * 8];
    float4 a1 = *(const float4*)&xs[k * 8 + 4];
    acc[0] += a0.x * w; acc[1] += a0.y * w; acc[2] += a0.z * w; acc[3] += a0.w * w;
    acc[4] += a1.x * w; acc[5] += a1.y * w; acc[6] += a1.z * w; acc[7] += a1.w * w;
  }
  #pragma unroll
  for (int r = 0; r < 8; r++)
    SXP[(size_t)(kc * 128 + rt * 8 + r) * 2048 + n] = acc[r];
}

// ------------------------------------------------------- sx reduce: fixed-order sum + scatter
// SX layout: [bh][e2(256)][u(64)]
__global__ __launch_bounds__(256) void sx_reduce(
    const float* __restrict__ SXP, float* __restrict__ SX) {
  const int bu = blockIdx.y;
  const int n = blockIdx.x * 256 + threadIdx.x;
  float s = 0.f;
  #pragma unroll
  for (int kc = 0; kc < 8; kc++)
    s += SXP[(size_t)(kc * 128 + bu) * 2048 + n];
  const int head = (n >> 7) & 7;
  const int e2 = ((n >> 10) << 7) | (n & 127);
  const int b = bu >> 6, u = bu & 63;
  SX[((size_t)((b * 8 + head) * 256) + e2) * 64 + u] = s;
}

// ------------------------------------------------------- sortnet + sinkhorn + top1 (fp32, LDS-staged)
// Sinkhorn reductions via 4-adjacent-lane shuffles (bitwise-identical combine order).
__global__ __launch_bounds__(256) void sortnet_sinkhorn(
    const float* __restrict__ SX, const float* __restrict__ sortw,
    const float* __restrict__ gum, int* __restrict__ idxArr,
    float* __restrict__ wgtArr) {
  __shared__ float sxl[64 * 64];  // chunk: [e][u]  16 KB
  __shared__ float wl[64 * 64];   // chunk: [e][c]  16 KB
  __shared__ float rr[64 * 65];   // 16.6 KB
  const int bh = blockIdx.x, tid = threadIdx.x, head = bh & 7;
  const int ui = tid & 15, ci = tid >> 4;  // 4x4 tile position

  float acc[4][4];
  #pragma unroll
  for (int i = 0; i < 4; i++)
    #pragma unroll
    for (int j = 0; j < 4; j++) acc[i][j] = 0.f;

  const f32x4* SX4 = (const f32x4*)(SX + (size_t)bh * 16384);
  const f32x4* W4 = (const f32x4*)(sortw + (size_t)head * 16384);
  f32x4* sxl4 = (f32x4*)sxl;
  f32x4* wl4 = (f32x4*)wl;

  #pragma unroll 1
  for (int ch = 0; ch < 4; ch++) {
    __syncthreads();
    #pragma unroll 1
    for (int g = tid; g < 1024; g += 256) {
      sxl4[g] = SX4[ch * 1024 + g];
      wl4[g] = W4[ch * 1024 + g];
    }
    __syncthreads();
    #pragma unroll 2
    for (int e = 0; e < 64; e++) {
      f32x4 a = sxl4[e * 16 + ui];
      f32x4 w = wl4[e * 16 + ci];
      #pragma unroll
      for (int i = 0; i < 4; i++)
        #pragma unroll
        for (int j = 0; j < 4; j++) acc[i][j] += a[i] * w[j];
    }
  }

  // leaky relu + gumbel + log -> rr
  #pragma unroll
  for (int i = 0; i < 4; i++)
    #pragma unroll
    for (int j = 0; j < 4; j++) {
      int u = ui * 4 + i, c = ci * 4 + j;
      float dot = acc[i][j];
      float r0 = dot > 0.f ? dot : 0.01f * dot;
      float gu = gum[(size_t)bh * 4096 + u * 64 + c];
      float inner = -logf(gu + EPS_) + EPS_;
      float g = -logf(fmaxf(inner, 1e-38f));
      rr[u * 65 + c] = (logf(fmaxf(r0 + EPS_, EPS_)) + g) / TEMP_;
    }
  __syncthreads();

  // 4 adjacent lanes own one row (row norm) / one col (col norm); qq = quarter.
  const int row4 = tid >> 2, qq = tid & 3;
  #pragma unroll 1
  for (int it = 0; it < 5; it++) {
    {  // row norm (axis c)
      float pm = -1e30f;
      #pragma unroll
      for (int j = 0; j < 16; j++) pm = fmaxf(pm, rr[row4 * 65 + qq * 16 + j]);
      float m0 = __shfl(pm, 0, 4), m1 = __shfl(pm, 1, 4);
      float m2 = __shfl(pm, 2, 4), m3 = __shfl(pm, 3, 4);
      float m = fmaxf(fmaxf(m0, m1), fmaxf(m2, m3));
      float ps = 0.f;
      #pragma unroll
      for (int j = 0; j < 16; j++) ps += expf(rr[row4 * 65 + qq * 16 + j] - m);
      float s0 = __shfl(ps, 0, 4), s1 = __shfl(ps, 1, 4);
      float s2 = __shfl(ps, 2, 4), s3 = __shfl(ps, 3, 4);
      float l = m + logf(((s0 + s1) + s2) + s3);
      #pragma unroll
      for (int j = 0; j < 16; j++) rr[row4 * 65 + qq * 16 + j] -= l;
      __syncthreads();
    }
    {  // col norm (axis u)
      float pm = -1e30f;
      #pragma unroll
      for (int j = 0; j < 16; j++) pm = fmaxf(pm, rr[(qq * 16 + j) * 65 + row4]);
      float m0 = __shfl(pm, 0, 4), m1 = __shfl(pm, 1, 4);
      float m2 = __shfl(pm, 2, 4), m3 = __shfl(pm, 3, 4);
      float m = fmaxf(fmaxf(m0, m1), fmaxf(m2, m3));
      float ps = 0.f;
      #pragma unroll
      for (int j = 0; j < 16; j++) ps += expf(rr[(qq * 16 + j) * 65 + row4] - m);
      float s0 = __shfl(ps, 0, 4), s1 = __shfl(ps, 1, 4);
      float s2 = __shfl(ps, 2, 4), s3 = __shfl(ps, 3, 4);
      float l = m + logf(((s0 + s1) + s2) + s3);
      #pragma unroll
      for (int j = 0; j < 16; j++) rr[(qq * 16 + j) * 65 + row4] -= l;
      __syncthreads();
    }
  }

  {  // first-max argmax over cols (np semantics): per-quarter scan then q-ascending strict >
    float pv = -1e30f;
    int pi = 0;
    #pragma unroll
    for (int j = 0; j < 16; j++) {
      float v = rr[row4 * 65 + qq * 16 + j];
      if (v > pv) { pv = v; pi = qq * 16 + j; }
    }
    float v0 = __shfl(pv, 0, 4); int i0 = __shfl(pi, 0, 4);
    float v1 = __shfl(pv, 1, 4); int i1 = __shfl(pi, 1, 4);
    float v2 = __shfl(pv, 2, 4); int i2 = __shfl(pi, 2, 4);
    float v3 = __shfl(pv, 3, 4); int i3 = __shfl(pi, 3, 4);
    float best = -1e30f;
    int bi = 0;
    if (v0 > best) { best = v0; bi = i0; }
    if (v1 > best) { best = v1; bi = i1; }
    if (v2 > best) { best = v2; bi = i2; }
    if (v3 > best) { best = v3; bi = i3; }
    if (qq == 0) {
      idxArr[bh * 64 + row4] = bi;
      wgtArr[bh * 64 + row4] = expf(fminf(best, 80.f));
    }
  }
}

// ------------------------------------------------------- QKV GEMM: r8 schedule + by-fastest
// XCD chunk traversal (FETCH 90->49 MB measured, r12). Bijective: by <-> (xcd, c&7), bx <-> c>>3.
__global__ __launch_bounds__(256, 2) void gemm_qkv(
    const ushort* __restrict__ A, const ushort* __restrict__ BT,
    ushort* __restrict__ Qb, ushort* __restrict__ Kb, ushort* __restrict__ VT) {
  const int K = 1024;
  __shared__ ushort As[2][128 * 64];
  __shared__ ushort Bs[2][128 * 64];
  const int tid = threadIdx.x;
  const int wave = tid >> 6, lane = tid & 63;
  const int quad = lane >> 4, l16 = lane & 15;
  const int gx = gridDim.x;
  const int lin = blockIdx.y * gx + blockIdx.x;
  const int xcd = lin & 7, c = lin >> 3;  // dispatch-linear -> XCD, chunk-local index
  const int by = xcd * 8 + (c & 7);       // by-fastest within chunk
  const int bx = c >> 3;
  const int m0 = by * 128, n0 = bx * 128;
  const int wm = (wave >> 1) * 64, wn = (wave & 1) * 64;
  const ushort* Ap = A + (uint64_t)m0 * K;
  const ushort* Bp = BT + (uint64_t)n0 * K;

  auto stage = [&](const ushort* G, int k0, ushort* buf) {
    #pragma unroll
    for (int q = 0; q < 4; ++q) {
      int p = q * 256 + tid;
      int row = p >> 3, pp = p & 7;
      int cc = pp ^ (row & 7);
      async_ld16(G + (uint64_t)row * K + k0 + cc * 8,
                 buf + (q * 256 + wave * 64) * 8);
    }
  };

  const uint32_t asB = lds_u32(&As[0][0]);
  const uint32_t bsB = lds_u32(&Bs[0][0]);
  uint32_t aoff[2][4], boff[2][4];
  #pragma unroll
  for (int kk = 0; kk < 2; ++kk) {
    int pc = (kk * 4 + quad) ^ (l16 & 7);
    #pragma unroll
    for (int mt = 0; mt < 4; ++mt) {
      aoff[kk][mt] = (uint32_t)((wm + mt * 16 + l16) * 128 + pc * 16);
      boff[kk][mt] = (uint32_t)((wn + mt * 16 + l16) * 128 + pc * 16);
    }
  }

  f32x4 acc[4][4];
  #pragma unroll
  for (int i = 0; i < 4; i++)
    #pragma unroll
    for (int j = 0; j < 4; j++) acc[i][j] = (f32x4){0.f, 0.f, 0.f, 0.f};

  const int NT = K >> 6;  // 16
  stage(Ap, 0, As[0]);
  stage(Bp, 0, Bs[0]);
  stage(Ap, 64, As[1]);
  stage(Bp, 64, Bs[1]);

  #pragma unroll 1
  for (int t = 0; t < NT; ++t) {
    if (t < NT - 1)
      asm volatile("s_waitcnt vmcnt(8)\n\ts_barrier" ::: "memory");
    else
      asm volatile("s_waitcnt vmcnt(0)\n\ts_barrier" ::: "memory");

    const uint32_t ab = asB + (uint32_t)(t & 1) * 16384u;
    const uint32_t bb = bsB + (uint32_t)(t & 1) * 16384u;
    bf16x8 a[2][4], b[2][4];
    #pragma unroll
    for (int kk = 0; kk < 2; ++kk) {
      #pragma unroll
      for (int mt = 0; mt < 4; ++mt) a[kk][mt] = dsr(ab + aoff[kk][mt]);
      #pragma unroll
      for (int nt = 0; nt < 4; ++nt) b[kk][nt] = dsr(bb + boff[kk][nt]);
    }
    asm volatile("s_waitcnt lgkmcnt(8)" ::: "memory");
    __builtin_amdgcn_sched_barrier(0);
    __builtin_amdgcn_s_setprio(1);
    #pragma unroll
    for (int mt = 0; mt < 4; ++mt)
      #pragma unroll
      for (int nt = 0; nt < 4; ++nt)
        acc[mt][nt] = __builtin_amdgcn_mfma_f32_16x16x32_bf16(a[0][mt], b[0][nt], acc[mt][nt], 0, 0, 0);
    __builtin_amdgcn_s_setprio(0);
    asm volatile("s_waitcnt lgkmcnt(0)" ::: "memory");
    __builtin_amdgcn_sched_barrier(0);
    __builtin_amdgcn_s_setprio(1);
    #pragma unroll
    for (int mt = 0; mt < 4; ++mt)
      #pragma unroll
      for (int nt = 0; nt < 4; ++nt)
        acc[mt][nt] = __builtin_amdgcn_mfma_f32_16x16x32_bf16(a[1][mt], b[1][nt], acc[mt][nt], 0, 0, 0);
    __builtin_amdgcn_s_setprio(0);
    asm volatile("s_barrier" ::: "memory");
    if (t + 2 < NT) {
      stage(Ap, (t + 2) * 64, As[t & 1]);
      stage(Bp, (t + 2) * 64, Bs[t & 1]);
    }
  }

  int which = bx >> 3;  // 0=q,1=k,2=v  (n0 multiple of 128)
  int head = bx & 7;
  #pragma unroll
  for (int mt = 0; mt < 4; mt++) {
    int mrow = m0 + wm + mt * 16 + quad * 4;
    int bidx = mrow >> 12;
    int ttok = mrow & 4095;
    int u = ttok >> 6, pos = ttok & 63;
    int bh = bidx * 8 + head;
    #pragma unroll
    for (int nt = 0; nt < 4; nt++) {
      int e = wn + nt * 16 + l16;
      if (which == 2) {
        ushort4 pk;
        pk.x = f2b(acc[mt][nt][0]);
        pk.y = f2b(acc[mt][nt][1]);
        pk.z = f2b(acc[mt][nt][2]);
        pk.w = f2b(acc[mt][nt][3]);
        *(ushort4*)&VT[((uint64_t)(bh * 64 + u) * 128 + e) * 64 + pos] = pk;
      } else {
        ushort* dst = (which == 0) ? Qb : Kb;
        #pragma unroll
        for (int r = 0; r < 4; r++)
          dst[((uint64_t)(bh * 64 + u) * 64 + pos + r) * 128 + e] = f2b(acc[mt][nt][r]);
      }
    }
  }
}

// ------------------------------------------------------- out-proj GEMM: gemm_qkv clone + the
// same by-fastest XCD traversal (chunk = 8 by x 8 bx; 8 consecutive same-XCD blocks share one
// 256KB B panel, chunk's 2MB A stays L2-resident). Bijective on grid (8,64).
__global__ __launch_bounds__(256, 2) void gemm_out(
    const ushort* __restrict__ A, const ushort* __restrict__ BT,
    const float* __restrict__ bias, float* __restrict__ Cout) {
  const int K = 1024, N = 1024;
  __shared__ ushort As[2][128 * 64];
  __shared__ ushort Bs[2][128 * 64];
  const int tid = threadIdx.x;
  const int wave = tid >> 6, lane = tid & 63;
  const int quad = lane >> 4, l16 = lane & 15;
  const int gx = gridDim.x;
  const int lin = blockIdx.y * gx + blockIdx.x;
  const int xcd = lin & 7, c = lin >> 3;  // c in [0,64)
  const int by = xcd * 8 + (c & 7);       // by-fastest within chunk
  const int bx = c >> 3;
  const int m0 = by * 128, n0 = bx * 128;
  const int wm = (wave >> 1) * 64, wn = (wave & 1) * 64;
  const ushort* Ap = A + (uint64_t)m0 * K;
  const ushort* Bp = BT + (uint64_t)n0 * K;

  auto stage = [&](const ushort* G, int k0, ushort* buf) {
    #pragma unroll
    for (int q = 0; q < 4; ++q) {
      int p = q * 256 + tid;
      int row = p >> 3, pp = p & 7;
      int cc = pp ^ (row & 7);
      async_ld16(G + (uint64_t)row * K + k0 + cc * 8,
                 buf + (q * 256 + wave * 64) * 8);
    }
  };

  const uint32_t asB = lds_u32(&As[0][0]);
  const uint32_t bsB = lds_u32(&Bs[0][0]);
  uint32_t aoff[2][4], boff[2][4];
  #pragma unroll
  for (int kk = 0; kk < 2; ++kk) {
    int pc = (kk * 4 + quad) ^ (l16 & 7);
    #pragma unroll
    for (int mt = 0; mt < 4; ++mt) {
      aoff[kk][mt] = (uint32_t)((wm + mt * 16 + l16) * 128 + pc * 16);
      boff[kk][mt] = (uint32_t)((wn + mt * 16 + l16) * 128 + pc * 16);
    }
  }

  f32x4 acc[4][4];
  #pragma unroll
  for (int i = 0; i < 4; i++)
    #pragma unroll
    for (int j = 0; j < 4; j++) acc[i][j] = (f32x4){0.f, 0.f, 0.f, 0.f};

  const int NT = K >> 6;  // 16
  stage(Ap, 0, As[0]);
  stage(Bp, 0, Bs[0]);
  stage(Ap, 64, As[1]);
  stage(Bp, 64, Bs[1]);

  #pragma unroll 1
  for (int t = 0; t < NT; ++t) {
    if (t < NT - 1)
      asm volatile("s_waitcnt vmcnt(8)\n\ts_barrier" ::: "memory");
    else
      asm volatile("s_waitcnt vmcnt(0)\n\ts_barrier" ::: "memory");

    const uint32_t ab = asB + (uint32_t)(t & 1) * 16384u;
    const uint32_t bb = bsB + (uint32_t)(t & 1) * 16384u;
    bf16x8 a[2][4], b[2][4];
    #pragma unroll
    for (int kk = 0; kk < 2; ++kk) {
      #pragma unroll
      for (int mt = 0; mt < 4; ++mt) a[kk][mt] = dsr(ab + aoff[kk][mt]);
      #pragma unroll
      for (int nt = 0; nt < 4; ++nt) b[kk][nt] = dsr(bb + boff[kk][nt]);
    }
    asm volatile("s_waitcnt lgkmcnt(8)" ::: "memory");
    __builtin_amdgcn_sched_barrier(0);
    __builtin_amdgcn_s_setprio(1);
    #pragma unroll
    for (int mt = 0; mt < 4; ++mt)
      #pragma unroll
      for (int nt = 0; nt < 4; ++nt)
        acc[mt][nt] = __builtin_amdgcn_mfma_f32_16x16x32_bf16(a[0][mt], b[0][nt], acc[mt][nt], 0, 0, 0);
    __builtin_amdgcn_s_setprio(0);
    asm volatile("s_waitcnt lgkmcnt(0)" ::: "memory");
    __builtin_amdgcn_sched_barrier(0);
    __builtin_amdgcn_s_setprio(1);
    #pragma unroll
    for (int mt = 0; mt < 4; ++mt)
      #pragma unroll
      for (int nt = 0; nt < 4; ++nt)
        acc[mt][nt] = __builtin_amdgcn_mfma_f32_16x16x32_bf16(a[1][mt], b[1][nt], acc[mt][nt], 0, 0, 0);
    __builtin_amdgcn_s_setprio(0);
    asm volatile("s_barrier" ::: "memory");
    if (t + 2 < NT) {
      stage(Ap, (t + 2) * 64, As[t & 1]);
      stage(Bp, (t + 2) * 64, Bs[t & 1]);
    }
  }

  #pragma unroll
  for (int mt = 0; mt < 4; mt++) {
    int row = m0 + wm + mt * 16 + quad * 4;
    #pragma unroll
    for (int nt = 0; nt < 4; nt++) {
      int col = n0 + wn + nt * 16 + l16;
      float bv = bias[col];
      #pragma unroll
      for (int r = 0; r < 4; r++)
        Cout[(uint64_t)(row + r) * N + col] = acc[mt][nt][r] + bv;
    }
  }
}

// ------------------------------------------------------- bucketed attention
// XCD-affine block remap: each XCD owns whole bh groups (bh = (c>>6)*8 + xcd, u = c&63) so the
// 3MB Qb/Kb/VT slice of a bh stays in one L2 (bijective on [0,1024)).
#define KSTR 136
__global__ __launch_bounds__(256) void attn_kernel(
    const ushort* __restrict__ Qb, const ushort* __restrict__ Kb,
    const ushort* __restrict__ VT, const int* __restrict__ idxArr,
    const float* __restrict__ wgtArr, ushort* __restrict__ attn_out) {
  __shared__ ushort Qs[64 * KSTR];   // Q, later P
  __shared__ ushort Ks[128 * KSTR];  // K2[j][e], later V2^T[e][j]
  const int lin = blockIdx.x;
  const int xcd = lin & 7, c = lin >> 3;
  const int bh = (c >> 6) * 8 + xcd;
  const int u = c & 63;
  const int tid = threadIdx.x, wave = tid >> 6, lane = tid & 63;
  const int quad = lane >> 4, l16 = lane & 15;
  const int vu = idxArr[bh * 64 + u] & 63;
  const float w = wgtArr[bh * 64 + u];

  const ushort* Qsrc = Qb + (uint64_t)(bh * 64 + u) * 8192;
  const ushort* Ksrc0 = Kb + (uint64_t)(bh * 64 + vu) * 8192;
  const ushort* Ksrc1 = Kb + (uint64_t)(bh * 64 + u) * 8192;
  const ushort* Vsrc0 = VT + (uint64_t)(bh * 64 + vu) * 8192;
  const ushort* Vsrc1 = VT + (uint64_t)(bh * 64 + u) * 8192;

  for (int g = tid; g < 64 * 16; g += 256) {
    int eb = g & 15, p = g >> 4;
    *(bf16x8*)&Qs[p * KSTR + eb * 8] = *(const bf16x8*)&Qsrc[p * 128 + eb * 8];
  }
  for (int g = tid; g < 128 * 16; g += 256) {
    int eb = g & 15, j = g >> 4;
    const ushort* s = (j < 64) ? &Ksrc0[j * 128 + eb * 8] : &Ksrc1[(j - 64) * 128 + eb * 8];
    *(bf16x8*)&Ks[j * KSTR + eb * 8] = *(const bf16x8*)s;
  }
  __syncthreads();

  f32x4 S[8];
  #pragma unroll
  for (int nt = 0; nt < 8; nt++) S[nt] = (f32x4){0.f, 0.f, 0.f, 0.f};
  #pragma unroll
  for (int kk = 0; kk < 4; kk++) {
    bf16x8 aq = *(const bf16x8*)&Qs[(wave * 16 + l16) * KSTR + kk * 32 + quad * 8];
    #pragma unroll
    for (int nt = 0; nt < 8; nt++) {
      bf16x8 bk = *(const bf16x8*)&Ks[(nt * 16 + l16) * KSTR + kk * 32 + quad * 8];
      S[nt] = __builtin_amdgcn_mfma_f32_16x16x32_bf16(aq, bk, S[nt], 0, 0, 0);
    }
  }
  __syncthreads();  // all waves done reading K2

  // stage V2^T into Ks
  for (int g = tid; g < 128 * 16; g += 256) {
    int jb = g & 15, e = g >> 4;
    const ushort* s = (jb < 8) ? &Vsrc0[e * 64 + jb * 8] : &Vsrc1[e * 64 + (jb - 8) * 8];
    *(bf16x8*)&Ks[e * KSTR + jb * 8] = *(const bf16x8*)s;
  }

  const float scale = 0.03125f;  // (d=1024)^-0.5
  float rowmax[4] = {-1e30f, -1e30f, -1e30f, -1e30f};
  #pragma unroll
  for (int nt = 0; nt < 8; nt++) {
    float cs = scale * ((nt < 4) ? w : 1.0f);
    #pragma unroll
    for (int r = 0; r < 4; r++) {
      S[nt][r] *= cs;
      rowmax[r] = fmaxf(rowmax[r], S[nt][r]);
    }
  }
  #pragma unroll
  for (int off = 1; off < 16; off <<= 1)
    #pragma unroll
    for (int r = 0; r < 4; r++)
      rowmax[r] = fmaxf(rowmax[r], __shfl_xor(rowmax[r], off, 64));
  float rowsum[4] = {0.f, 0.f, 0.f, 0.f};
  #pragma unroll
  for (int nt = 0; nt < 8; nt++)
    #pragma unroll
    for (int r = 0; r < 4; r++) {
      float p = expf(S[nt][r] - rowmax[r]);
      S[nt][r] = p;
      rowsum[r] += p;
    }
  #pragma unroll
  for (int off = 1; off < 16; off <<= 1)
    #pragma unroll
    for (int r = 0; r < 4; r++)
      rowsum[r] += __shfl_xor(rowsum[r], off, 64);
  float rinv[4];
  #pragma unroll
  for (int r = 0; r < 4; r++) rinv[r] = 1.0f / rowsum[r];

  #pragma unroll
  for (int nt = 0; nt < 8; nt++)
    #pragma unroll
    for (int r = 0; r < 4; r++) {
      float pv = S[nt][r] * rinv[r] * ((nt < 4) ? w : 1.0f);
      Qs[(wave * 16 + quad * 4 + r) * KSTR + nt * 16 + l16] = f2b(pv);
    }
  __syncthreads();  // V2^T staged

  f32x4 O[8];
  #pragma unroll
  for (int nt = 0; nt < 8; nt++) O[nt] = (f32x4){0.f, 0.f, 0.f, 0.f};
  #pragma unroll
  for (int kk = 0; kk < 4; kk++) {
    bf16x8 ap = *(const bf16x8*)&Qs[(wave * 16 + l16) * KSTR + kk * 32 + quad * 8];
    #pragma unroll
    for (int nt = 0; nt < 8; nt++) {
      bf16x8 bv = *(const bf16x8*)&Ks[(nt * 16 + l16) * KSTR + kk * 32 + quad * 8];
      O[nt] = __builtin_amdgcn_mfma_f32_16x16x32_bf16(ap, bv, O[nt], 0, 0, 0);
    }
  }

  const int bidx = bh >> 3, head = bh & 7;
  uint64_t rowbase =
      (uint64_t)(bidx * 4096 + u * 64 + wave * 16 + quad * 4) * 1024 + head * 128;
  #pragma unroll
  for (int nt = 0; nt < 8; nt++)
    #pragma unroll
    for (int r = 0; r < 4; r++)
      attn_out[rowbase + (uint64_t)r * 1024 + nt * 16 + l16] = f2b(O[nt][r]);
}

// ---------------------------------------------------------------- launch
extern "C" void kernel_launch(void* const* d_in, const int* in_sizes, int n_in,
                              void* d_out, int out_size, void* d_ws, size_t ws_size,
                              hipStream_t stream) {
  (void)in_sizes; (void)n_in; (void)out_size; (void)ws_size;
  const float* x = (const float*)d_in[0];      // (2,4096,1024) fp32
  const float* gum = (const float*)d_in[1];    // (16,64,64) fp32
  const float* wqkv = (const float*)d_in[2];   // (1024,3072) fp32
  const float* sortw = (const float*)d_in[3];  // (1,8,256,64) fp32
  const float* wout = (const float*)d_in[4];   // (1024,1024) fp32
  const float* bout = (const float*)d_in[5];   // (1024,) fp32
  float* out = (float*)d_out;                  // (2,4096,1024) fp32

  char* ws = (char*)d_ws;
  size_t off = 0;
  auto alloc = [&](size_t bytes) {
    char* p = ws + off;
    off += (bytes + 255) & ~(size_t)255;
    return p;
  };
  ushort* xb = (ushort*)alloc((size_t)8192 * 1024 * 2);
  float* xsum2 = (float*)alloc((size_t)256 * 1024 * 4);
  ushort* wqkvT = (ushort*)alloc((size_t)3072 * 1024 * 2);
  ushort* woutT = (ushort*)alloc((size_t)1024 * 1024 * 2);
  float* SX = (float*)alloc((size_t)16 * 256 * 64 * 4);
  ushort* Qb = (ushort*)alloc((size_t)16 * 64 * 64 * 128 * 2);
  ushort* Kb = (ushort*)alloc((size_t)16 * 64 * 64 * 128 * 2);
  ushort* VT = (ushort*)alloc((size_t)16 * 64 * 128 * 64 * 2);
  int* idxArr = (int*)alloc((size_t)16 * 64 * 4);
  float* wgtArr = (float*)alloc((size_t)16 * 64 * 4);
  ushort* attn = xb;        // alias: xb dead after qkv gemm
  float* SXP = (float*)Qb;  // alias: 8 MB partials, dead before Qb written

  prep_x<<<512, 256, 0, stream>>>(x, xb, xsum2);
  transpose_f2b<<<dim3(3072 / 32, 1024 / 32), 256, 0, stream>>>(wqkv, wqkvT, 1024, 3072);
  transpose_f2b<<<dim3(1024 / 32, 1024 / 32), 256, 0, stream>>>(wout, woutT, 1024, 1024);
  sx_gemm_partial<<<dim3(8, 16, 8), 256, 0, stream>>>(xsum2, wqkv, SXP);
  sx_reduce<<<dim3(8, 128), 256, 0, stream>>>(SXP, SX);
  sortnet_sinkhorn<<<16, 256, 0, stream>>>(SX, sortw, gum, idxArr, wgtArr);
  gemm_qkv<<<dim3(3072 / 128, 8192 / 128), 256, 0, stream>>>(xb, wqkvT, Qb, Kb, VT);
  attn_kernel<<<16 * 64, 256, 0, stream>>>(Qb, Kb, VT, idxArr, wgtArr, attn);
  gemm_out<<<dim3(1024 / 128, 8192 / 128), 256, 0, stream>>>(attn, woutT, bout, out);
}